// Round 8
// baseline (284.837 us; speedup 1.0000x reference)
//
#include <hip/hip_runtime.h>
#include <cstdint>
#include <cstddef>

// B=32, D=256, H=W=32 (HW=1024), S=2048, N=32768
#define D_DIM 256
#define S_SLOTS 2048
#define HW_PIX 1024
#define OUT_ENT_IDX 8388608
#define OUT_WIMG_IDX 8388609

// k_fused dynamic LDS
#define BUFA_OFF(b) ((b) * 32768)            // mhat tiles: [0, 65536)
#define BUFB_OFF(b) (65536 + (b) * 32768)    // mblk tiles: [65536, 131072)
#define WIMG_OFF    131072                   // f32[2048]
#define FUSED_DYN   139264

#define LOG2E_20 28.853900817779268f
#define LN2F     0.6931471805599453f

using short8 = __attribute__((ext_vector_type(8))) short;
using f32x4  = __attribute__((ext_vector_type(4))) float;

__device__ __forceinline__ unsigned short f2bf(float x) {
    union { float f; unsigned u; } v; v.f = x;
    unsigned r = v.u + 0x7FFF + ((v.u >> 16) & 1);   // RNE
    return (unsigned short)(r >> 16);
}
__device__ __forceinline__ unsigned pack2(float lo, float hi) {
    return (unsigned)f2bf(lo) | ((unsigned)f2bf(hi) << 16);
}
__device__ __forceinline__ void gload16(const void* g, void* l) {
    __builtin_amdgcn_global_load_lds(
        (const __attribute__((address_space(1))) unsigned int*)g,
        (__attribute__((address_space(3))) unsigned int*)l, 16, 0, 0);
}

// ---------------- prep: norms + three bf16 layouts into ws (coalesced) ------
// mhatg: [s][d] bf16, scaled by (20*log2e)/||m_s||, chunk swizzle ^(s&7) (1MB)
// mblkg: [tile][d 256][sloc 64] bf16 raw, chunk swizzle ^(d&7)           (1MB)
// mqkg : A-frag-linear: [(tile*2+ws)*8+kk][sb][lane(g*16+l15)][8 bf16]   (1MB)
//        element (s = 64*tile+32*ws+16*sb+l15, d = 32*kk+8*g+i), scaled
__global__ __launch_bounds__(64) void k_prep(const float* __restrict__ mem,
                                             unsigned short* __restrict__ mhatg,
                                             unsigned short* __restrict__ mblkg,
                                             unsigned short* __restrict__ mqkg) {
    __shared__ float lm[8 * 257];
    __shared__ float scl[8];
    const int l = threadIdx.x, blk = blockIdx.x;
    const int tile = blk >> 3, oct = blk & 7;
    const int s0 = tile * 64 + oct * 8;
    const float* src = mem + (size_t)s0 * D_DIM;
#pragma unroll
    for (int i = 0; i < 8; ++i) {
        const int f4 = i * 64 + l;
        const int r = f4 >> 6, dq = (f4 & 63) * 4;
        const float4 v = reinterpret_cast<const float4*>(src)[f4];
        float* p = lm + r * 257 + dq;
        p[0] = v.x; p[1] = v.y; p[2] = v.z; p[3] = v.w;
    }
    __syncthreads();
    {
        const int r = l >> 3, pp = l & 7;
        float ss = 0.f;
#pragma unroll 8
        for (int d = 0; d < 32; ++d) { const float v = lm[r * 257 + pp * 32 + d]; ss += v * v; }
        ss += __shfl_xor(ss, 1); ss += __shfl_xor(ss, 2); ss += __shfl_xor(ss, 4);
        if (pp == 0) scl[r] = LOG2E_20 / fmaxf(sqrtf(ss), 1e-12f);
    }
    __syncthreads();
    // mhat: 8 rows x 32 chunks of 16B
#pragma unroll
    for (int i = 0; i < 4; ++i) {
        const int c = i * 64 + l, r = c >> 5, k = c & 31;
        const int s_g = s0 + r;
        const float sc = scl[r];
        const float* p = lm + r * 257 + ((k ^ (s_g & 7)) * 8);
        union { short8 s; unsigned short h[8]; } o;
#pragma unroll
        for (int j = 0; j < 8; ++j) o.h[j] = f2bf(p[j] * sc);
        *reinterpret_cast<short8*>((char*)mhatg + (size_t)s_g * 512 + k * 16) = o.s;
    }
    // mblk: 256 d-rows, this octet fills chunk k = oct^(d&7) of each row (raw)
#pragma unroll
    for (int i = 0; i < 4; ++i) {
        const int d = i * 64 + l;
        const int k = oct ^ (d & 7);
        union { short8 s; unsigned short h[8]; } o;
#pragma unroll
        for (int j = 0; j < 8; ++j) o.h[j] = f2bf(lm[j * 257 + d]);
        *reinterpret_cast<short8*>((char*)mblkg + (size_t)tile * 32768 + d * 128 + k * 16) = o.s;
    }
    // mqk: A-frag-linear scaled copy
    {
        const int ws_p = oct >> 2, sb = (oct >> 1) & 1, l15b = (oct & 1) * 8;
#pragma unroll
        for (int i = 0; i < 4; ++i) {
            const int c = i * 64 + l;             // 0..255
            const int kk = c >> 5, g = (c >> 3) & 3, j = c & 7;
            const float sc = scl[j];
            const float* p = lm + j * 257 + (32 * kk + 8 * g);
            union { short8 s; unsigned short h[8]; } o;
#pragma unroll
            for (int t = 0; t < 8; ++t) o.h[t] = f2bf(p[t] * sc);
            char* dst = (char*)mqkg + (size_t)(((tile * 2 + ws_p) * 8 + kk)) * 2048
                        + sb * 1024 + (g * 16 + l15b + j) * 16;
            *reinterpret_cast<short8*>(dst) = o.s;
        }
    }
}

// ---------------- k_fused: flash pass + epilogue + wimg phase ----------------
__device__ __forceinline__ void qkt(const char* mh, const short8 (&qfrag)[2][8],
                                    int srow, int g, int l15, f32x4 (&acc)[2][2]) {
#pragma unroll
    for (int kk = 0; kk < 8; ++kk) {
        const int c0 = ((4 * kk + g) ^ (l15 & 7)) << 4;
        const short8 a0 = *reinterpret_cast<const short8*>(mh + srow * 512 + c0);
        const short8 a1 = *reinterpret_cast<const short8*>(mh + (srow + 16) * 512 + c0);
        acc[0][0] = __builtin_amdgcn_mfma_f32_16x16x32_bf16(a0, qfrag[0][kk], acc[0][0], 0, 0, 0);
        acc[0][1] = __builtin_amdgcn_mfma_f32_16x16x32_bf16(a0, qfrag[1][kk], acc[0][1], 0, 0, 0);
        acc[1][0] = __builtin_amdgcn_mfma_f32_16x16x32_bf16(a1, qfrag[0][kk], acc[1][0], 0, 0, 0);
        acc[1][1] = __builtin_amdgcn_mfma_f32_16x16x32_bf16(a1, qfrag[1][kk], acc[1][1], 0, 0, 0);
    }
}

__global__ __launch_bounds__(512, 2) void k_fused(
    const float* __restrict__ feat, const char* __restrict__ mhat_g,
    const char* __restrict__ mblk_g, const char* __restrict__ mqk_g,
    float* __restrict__ out)
{
    extern __shared__ char dyn[];
    __shared__ float sm_norm[512];
    __shared__ float qs_lds[128];
    __shared__ float zb[2][4][2][16];
    __shared__ float ub[2][4][2][16];
    __shared__ float rZbuf[128];
    __shared__ float entb[4];

    const int tid  = threadIdx.x;
    const int lane = tid & 63;
    const int w    = tid >> 6;
    const int wq   = w & 3;
    const int ws   = w >> 2;
    const int l15  = lane & 15;
    const int g    = (lane >> 4) & 3;
    const int blk  = blockIdx.x;
    const int b    = blk >> 3;
    const int p0   = (blk & 7) * 128;
    const float* fbase = feat + (size_t)b * (D_DIM * HW_PIX);
    float* wimg_l = reinterpret_cast<float*>(dyn + WIMG_OFF);

    auto stageA = [&](int st, int buf) {
        const char* gsrc = mhat_g + (size_t)st * 32768;
        char* ldst = dyn + BUFA_OFF(buf);
#pragma unroll
        for (int i = 0; i < 4; ++i)
            gload16(gsrc + tid * 16 + i * 8192, ldst + tid * 16 + i * 8192);
    };
    auto stageB = [&](int st, int buf) {
        const char* gsrc = mblk_g + (size_t)st * 32768;
        char* ldst = dyn + BUFB_OFF(buf);
#pragma unroll
        for (int i = 0; i < 4; ++i)
            gload16(gsrc + tid * 16 + i * 8192, ldst + tid * 16 + i * 8192);
    };

    stageA(0, 0); stageB(0, 0);

    // zero per-block wimg accumulator
#pragma unroll
    for (int i = 0; i < 4; ++i) wimg_l[i * 512 + tid] = 0.f;

    // ---- query norms ----
    {
        const int dp = tid >> 7, pp = tid & 127;
        const float* fp = fbase + (size_t)(dp * 64) * HW_PIX + p0 + pp;
        float ss = 0.f;
#pragma unroll 8
        for (int d = 0; d < 64; ++d) { const float v = fp[(size_t)d * HW_PIX]; ss += v * v; }
        sm_norm[dp * 128 + pp] = ss;
    }
    __syncthreads();
    if (tid < 128) {
        const float n2 = sm_norm[tid] + sm_norm[128 + tid] + sm_norm[256 + tid] + sm_norm[384 + tid];
        qs_lds[tid] = 1.0f / fmaxf(sqrtf(n2), 1e-12f);
    }
    __syncthreads();

    // ---- Q fragments (bf16 q-hat) ----
    short8 qfrag[2][8];
#pragma unroll
    for (int tq = 0; tq < 2; ++tq) {
        const int q = 32 * wq + 16 * tq + l15;
        const float qs = qs_lds[q];
        const float* fq = fbase + p0 + q;
#pragma unroll
        for (int kk = 0; kk < 8; ++kk) {
            union { short8 s; unsigned u[4]; } fr;
#pragma unroll
            for (int jp = 0; jp < 4; ++jp) {
                const int d = 32 * kk + 8 * g + 2 * jp;
                fr.u[jp] = pack2(fq[(size_t)d * HW_PIX] * qs, fq[(size_t)(d + 1) * HW_PIX] * qs);
            }
            qfrag[tq][kk] = fr.s;
        }
    }

    const int srow = 32 * ws + l15;

    // ================= PHASE 1: Z, U, O_unnorm =================
    float Zp[2] = {0.f, 0.f}, Up[2] = {0.f, 0.f};
    f32x4 acc_o[2][16] = {};
    __syncthreads();
    int cur = 0;
    for (int st = 0; st < 32; ++st) {
        if (st < 31) { stageA(st + 1, cur ^ 1); stageB(st + 1, cur ^ 1); }
        f32x4 acc[2][2] = {};
        qkt(dyn + BUFA_OFF(cur), qfrag, srow, g, l15, acc);
        float ev[2][2][4];
#pragma unroll
        for (int ts = 0; ts < 2; ++ts)
#pragma unroll
            for (int tq = 0; tq < 2; ++tq)
#pragma unroll
                for (int r = 0; r < 4; ++r) {
                    const float sim2 = acc[ts][tq][r];       // log2-domain
                    const float e = exp2f(sim2);
                    ev[ts][tq][r] = e;
                    Zp[tq] += e; Up[tq] += e * sim2;
                }
        // repack P -> A-fragments (bf16 raw e), in registers
        short8 pfrag[2];
#pragma unroll
        for (int tq = 0; tq < 2; ++tq) {
            const unsigned u00 = pack2(ev[0][tq][0], ev[0][tq][1]);
            const unsigned u01 = pack2(ev[0][tq][2], ev[0][tq][3]);
            const unsigned u10 = pack2(ev[1][tq][0], ev[1][tq][1]);
            const unsigned u11 = pack2(ev[1][tq][2], ev[1][tq][3]);
            const int sA = l15 + 32 * (g & 1);
            const int sB = sA + 16;
            const unsigned a00 = __shfl((int)u00, sA), a10 = __shfl((int)u10, sA);
            const unsigned a01 = __shfl((int)u01, sA), a11 = __shfl((int)u11, sA);
            const unsigned b00 = __shfl((int)u00, sB), b10 = __shfl((int)u10, sB);
            const unsigned b01 = __shfl((int)u01, sB), b11 = __shfl((int)u11, sB);
            const bool hi = (lane & 32) != 0;
            union { short8 s; unsigned u[4]; } fr;
            fr.u[0] = hi ? a10 : a00;
            fr.u[1] = hi ? a11 : a01;
            fr.u[2] = hi ? b10 : b00;
            fr.u[3] = hi ? b11 : b01;
            pfrag[tq] = fr.s;
        }
        const char* mb = dyn + BUFB_OFF(cur);
        const int cswz = (((4 * ws + g) ^ (l15 & 7)) << 4);
#pragma unroll
        for (int Dt = 0; Dt < 16; ++Dt) {
            const int d = 16 * Dt + l15;
            const short8 bf = *reinterpret_cast<const short8*>(mb + d * 128 + cswz);
            acc_o[0][Dt] = __builtin_amdgcn_mfma_f32_16x16x32_bf16(pfrag[0], bf, acc_o[0][Dt], 0, 0, 0);
            acc_o[1][Dt] = __builtin_amdgcn_mfma_f32_16x16x32_bf16(pfrag[1], bf, acc_o[1][Dt], 0, 0, 0);
        }
        __syncthreads();
        cur ^= 1;
    }

    // ---- Z/U reduction, rZ, entropy (H = lnZ - ln2*U2/Z) ----
#pragma unroll
    for (int tq = 0; tq < 2; ++tq) {
        Zp[tq] += __shfl_xor(Zp[tq], 16); Zp[tq] += __shfl_xor(Zp[tq], 32);
        Up[tq] += __shfl_xor(Up[tq], 16); Up[tq] += __shfl_xor(Up[tq], 32);
    }
    if (lane < 16) {
#pragma unroll
        for (int tq = 0; tq < 2; ++tq) {
            zb[ws][wq][tq][lane] = Zp[tq];
            ub[ws][wq][tq][lane] = Up[tq];
        }
    }
    __syncthreads();
    {
        float Zf[2], Uf[2], rZ[2];
#pragma unroll
        for (int tq = 0; tq < 2; ++tq) {
            Zf[tq] = Zp[tq] + zb[1 - ws][wq][tq][l15];
            Uf[tq] = Up[tq] + ub[1 - ws][wq][tq][l15];
            rZ[tq] = 1.0f / Zf[tq];
        }
        if (ws == 0 && lane < 16) {
            rZbuf[32 * wq + l15]      = rZ[0];
            rZbuf[32 * wq + 16 + l15] = rZ[1];
            float ent = 0.f;
#pragma unroll
            for (int tq = 0; tq < 2; ++tq) ent += __logf(Zf[tq]) - LN2F * Uf[tq] * rZ[tq];
            ent += __shfl_xor(ent, 1); ent += __shfl_xor(ent, 2);
            ent += __shfl_xor(ent, 4); ent += __shfl_xor(ent, 8);
            if (lane == 0) entb[wq] = ent;
        }
    }
    __syncthreads();
    if (tid == 0)
        atomicAdd(out + OUT_ENT_IDX, (entb[0] + entb[1] + entb[2] + entb[3]) * (1.0f / 32768.0f));

    // ---- epilogue FIRST (frees acc_o before wimg phase) ----
    float rZq[2][4];
#pragma unroll
    for (int tq = 0; tq < 2; ++tq)
#pragma unroll
        for (int r = 0; r < 4; ++r)
            rZq[tq][r] = rZbuf[32 * wq + 16 * tq + 4 * g + r];

#pragma unroll
    for (int Dt = 0; Dt < 16; ++Dt) {
        if (ws == 1) {
#pragma unroll
            for (int tq = 0; tq < 2; ++tq)
                *reinterpret_cast<f32x4*>(dyn + ((wq * 2 + tq) * 64 + lane) * 16) = acc_o[tq][Dt];
        }
        __syncthreads();
        if (ws == 0) {
#pragma unroll
            for (int tq = 0; tq < 2; ++tq) {
                const f32x4 other = *reinterpret_cast<const f32x4*>(dyn + ((wq * 2 + tq) * 64 + lane) * 16);
#pragma unroll
                for (int r = 0; r < 4; ++r) {
                    const float o = (acc_o[tq][Dt][r] + other[r]) * rZq[tq][r];
                    const float a = fabsf(o);
                    const float lam = fminf(0.005f / (a + 1e-8f), 1.0f);
                    const float val = copysignf(a * (1.0f - lam), o);
                    const int q = 32 * wq + 16 * tq + 4 * g + r;
                    *reinterpret_cast<float*>(dyn + 8192 + q * 84 + l15 * 4) = val;
                }
            }
        }
        __syncthreads();
#pragma unroll
        for (int i = 0; i < 4; ++i) {
            const int flat = i * 512 + tid;
            const int dd = flat >> 7, q = flat & 127;
            const float val = *reinterpret_cast<const float*>(dyn + 8192 + q * 84 + dd * 4);
            out[((size_t)b * 256 + Dt * 16 + dd) * HW_PIX + p0 + q] = val;
        }
        __syncthreads();
    }

    // ================= PHASE 2: wimg (barrier-free, global-direct A) =========
    {
        float rzq[2][4];
#pragma unroll
        for (int tq = 0; tq < 2; ++tq)
#pragma unroll
            for (int r = 0; r < 4; ++r)
                rzq[tq][r] = rZbuf[32 * wq + 16 * tq + 4 * g + r] * (1.0f / 1024.0f);

        for (int st = 0; st < 32; ++st) {
            const char* tb = mqk_g + (size_t)((st * 2 + ws) * 8) * 2048 + lane * 16;
            f32x4 a2[2][2] = {};   // [sb][tq]
            short8 mc[2][2];
            mc[0][0] = *reinterpret_cast<const short8*>(tb);
            mc[0][1] = *reinterpret_cast<const short8*>(tb + 1024);
#pragma unroll
            for (int kk = 0; kk < 8; ++kk) {
                const int cu2 = kk & 1, nx = cu2 ^ 1;
                if (kk < 7) {
                    mc[nx][0] = *reinterpret_cast<const short8*>(tb + (kk + 1) * 2048);
                    mc[nx][1] = *reinterpret_cast<const short8*>(tb + (kk + 1) * 2048 + 1024);
                }
                a2[0][0] = __builtin_amdgcn_mfma_f32_16x16x32_bf16(qfrag[0][kk], mc[cu2][0], a2[0][0], 0, 0, 0);
                a2[0][1] = __builtin_amdgcn_mfma_f32_16x16x32_bf16(qfrag[1][kk], mc[cu2][0], a2[0][1], 0, 0, 0);
                a2[1][0] = __builtin_amdgcn_mfma_f32_16x16x32_bf16(qfrag[0][kk], mc[cu2][1], a2[1][0], 0, 0, 0);
                a2[1][1] = __builtin_amdgcn_mfma_f32_16x16x32_bf16(qfrag[1][kk], mc[cu2][1], a2[1][1], 0, 0, 0);
            }
#pragma unroll
            for (int sb = 0; sb < 2; ++sb) {
                float v = 0.f;
#pragma unroll
                for (int tq = 0; tq < 2; ++tq)
#pragma unroll
                    for (int r = 0; r < 4; ++r)
                        v += exp2f(a2[sb][tq][r]) * rzq[tq][r];
                v += __shfl_xor(v, 16);
                v += __shfl_xor(v, 32);
                if (lane < 16)
                    atomicAdd(&wimg_l[st * 64 + 32 * ws + 16 * sb + l15], v);
            }
        }
    }
    __syncthreads();
    {
        float* wimg_gb = out + OUT_WIMG_IDX + (size_t)b * S_SLOTS;
#pragma unroll
        for (int i = 0; i < 4; ++i) {
            const int s = i * 512 + tid;
            atomicAdd(wimg_gb + s, wimg_l[s]);
        }
    }
}

extern "C" void kernel_launch(void* const* d_in, const int* in_sizes, int n_in,
                              void* d_out, int out_size, void* d_ws, size_t ws_size,
                              hipStream_t stream) {
    const float* feat = (const float*)d_in[0];   // (32,256,32,32) f32
    const float* mem  = (const float*)d_in[1];   // (2048,256) f32
    float* out = (float*)d_out;

    unsigned short* mhat_g = (unsigned short*)d_ws;                       // 1 MB
    unsigned short* mblk_g = (unsigned short*)((char*)d_ws + (1 << 20));  // 1 MB
    unsigned short* mqk_g  = (unsigned short*)((char*)d_ws + (2 << 20));  // 1 MB

    // zero entropy + weights_image (retrieved fully overwritten)
    hipMemsetAsync((char*)d_out + (size_t)OUT_ENT_IDX * 4, 0,
                   (size_t)(1 + 32 * S_SLOTS) * 4, stream);

    k_prep<<<256, 64, 0, stream>>>(mem, mhat_g, mblk_g, mqk_g);

    hipFuncSetAttribute((const void*)k_fused,
                        hipFuncAttributeMaxDynamicSharedMemorySize, FUSED_DYN);
    k_fused<<<256, 512, FUSED_DYN, stream>>>(feat, (const char*)mhat_g,
                                             (const char*)mblk_g,
                                             (const char*)mqk_g, out);
}

// Round 9
// 274.155 us; speedup vs baseline: 1.0390x; 1.0390x over previous
//
#include <hip/hip_runtime.h>
#include <cstdint>
#include <cstddef>

// B=32, D=256, H=W=32 (HW=1024), S=2048, N=32768
#define D_DIM 256
#define S_SLOTS 2048
#define HW_PIX 1024
#define OUT_ENT_IDX 8388608
#define OUT_WIMG_IDX 8388609

// k_fused dynamic LDS
#define BUFA_OFF(b) ((b) * 32768)            // phase-1 mhat tiles: [0, 65536)
#define BUFB_OFF(b) (65536 + (b) * 32768)    // phase-1 mblk / phase-2 mhat tiles
#define WIMG_OFF    131072                   // f32[2048]
#define FUSED_DYN   139264

#define LOG2E_20 28.853900817779268f
#define LN2F     0.6931471805599453f

using short8 = __attribute__((ext_vector_type(8))) short;
using f32x4  = __attribute__((ext_vector_type(4))) float;

__device__ __forceinline__ unsigned short f2bf(float x) {
    union { float f; unsigned u; } v; v.f = x;
    unsigned r = v.u + 0x7FFF + ((v.u >> 16) & 1);   // RNE
    return (unsigned short)(r >> 16);
}
__device__ __forceinline__ unsigned pack2(float lo, float hi) {
    return (unsigned)f2bf(lo) | ((unsigned)f2bf(hi) << 16);
}
__device__ __forceinline__ void gload16(const void* g, void* l) {
    __builtin_amdgcn_global_load_lds(
        (const __attribute__((address_space(1))) unsigned int*)g,
        (__attribute__((address_space(3))) unsigned int*)l, 16, 0, 0);
}

// ---------------- prep: norms + two bf16 layouts into ws (coalesced) --------
// mhatg: [s][d] bf16, scaled by (20*log2e)/||m_s||, chunk swizzle ^(s&7) (1MB)
// mblkg: [tile][d 256][sloc 64] bf16 raw, chunk swizzle ^(d&7)           (1MB)
__global__ __launch_bounds__(64) void k_prep(const float* __restrict__ mem,
                                             unsigned short* __restrict__ mhatg,
                                             unsigned short* __restrict__ mblkg) {
    __shared__ float lm[8 * 257];
    __shared__ float scl[8];
    const int l = threadIdx.x, blk = blockIdx.x;
    const int tile = blk >> 3, oct = blk & 7;
    const int s0 = tile * 64 + oct * 8;
    const float* src = mem + (size_t)s0 * D_DIM;
#pragma unroll
    for (int i = 0; i < 8; ++i) {
        const int f4 = i * 64 + l;
        const int r = f4 >> 6, dq = (f4 & 63) * 4;
        const float4 v = reinterpret_cast<const float4*>(src)[f4];
        float* p = lm + r * 257 + dq;
        p[0] = v.x; p[1] = v.y; p[2] = v.z; p[3] = v.w;
    }
    __syncthreads();
    {
        const int r = l >> 3, pp = l & 7;
        float ss = 0.f;
#pragma unroll 8
        for (int d = 0; d < 32; ++d) { const float v = lm[r * 257 + pp * 32 + d]; ss += v * v; }
        ss += __shfl_xor(ss, 1); ss += __shfl_xor(ss, 2); ss += __shfl_xor(ss, 4);
        if (pp == 0) scl[r] = LOG2E_20 / fmaxf(sqrtf(ss), 1e-12f);
    }
    __syncthreads();
    // mhat: 8 rows x 32 chunks of 16B
#pragma unroll
    for (int i = 0; i < 4; ++i) {
        const int c = i * 64 + l, r = c >> 5, k = c & 31;
        const int s_g = s0 + r;
        const float sc = scl[r];
        const float* p = lm + r * 257 + ((k ^ (s_g & 7)) * 8);
        union { short8 s; unsigned short h[8]; } o;
#pragma unroll
        for (int j = 0; j < 8; ++j) o.h[j] = f2bf(p[j] * sc);
        *reinterpret_cast<short8*>((char*)mhatg + (size_t)s_g * 512 + k * 16) = o.s;
    }
    // mblk: 256 d-rows, this octet fills chunk k = oct^(d&7) of each row (raw)
#pragma unroll
    for (int i = 0; i < 4; ++i) {
        const int d = i * 64 + l;
        const int k = oct ^ (d & 7);
        union { short8 s; unsigned short h[8]; } o;
#pragma unroll
        for (int j = 0; j < 8; ++j) o.h[j] = f2bf(lm[j * 257 + d]);
        *reinterpret_cast<short8*>((char*)mblkg + (size_t)tile * 32768 + d * 128 + k * 16) = o.s;
    }
}

// ---------------- k_fused: flash pass + epilogue + LDS-staged wimg phase ----
__device__ __forceinline__ void qkt(const char* mh, const short8 (&qfrag)[2][8],
                                    int srow, int g, int l15, f32x4 (&acc)[2][2]) {
#pragma unroll
    for (int kk = 0; kk < 8; ++kk) {
        const int c0 = ((4 * kk + g) ^ (l15 & 7)) << 4;
        const short8 a0 = *reinterpret_cast<const short8*>(mh + srow * 512 + c0);
        const short8 a1 = *reinterpret_cast<const short8*>(mh + (srow + 16) * 512 + c0);
        acc[0][0] = __builtin_amdgcn_mfma_f32_16x16x32_bf16(a0, qfrag[0][kk], acc[0][0], 0, 0, 0);
        acc[0][1] = __builtin_amdgcn_mfma_f32_16x16x32_bf16(a0, qfrag[1][kk], acc[0][1], 0, 0, 0);
        acc[1][0] = __builtin_amdgcn_mfma_f32_16x16x32_bf16(a1, qfrag[0][kk], acc[1][0], 0, 0, 0);
        acc[1][1] = __builtin_amdgcn_mfma_f32_16x16x32_bf16(a1, qfrag[1][kk], acc[1][1], 0, 0, 0);
    }
}

__global__ __launch_bounds__(512, 2) void k_fused(
    const float* __restrict__ feat, const char* __restrict__ mhat_g,
    const char* __restrict__ mblk_g, float* __restrict__ out)
{
    extern __shared__ char dyn[];
    __shared__ float sm_norm[512];
    __shared__ float qs_lds[128];
    __shared__ float zb[2][4][2][16];
    __shared__ float ub[2][4][2][16];
    __shared__ float rZbuf[128];
    __shared__ float entb[4];

    const int tid  = threadIdx.x;
    const int lane = tid & 63;
    const int w    = tid >> 6;
    const int wq   = w & 3;
    const int ws   = w >> 2;
    const int l15  = lane & 15;
    const int g    = (lane >> 4) & 3;
    const int blk  = blockIdx.x;
    const int b    = blk >> 3;
    const int p0   = (blk & 7) * 128;
    const float* fbase = feat + (size_t)b * (D_DIM * HW_PIX);
    float* wimg_l = reinterpret_cast<float*>(dyn + WIMG_OFF);

    auto stageA = [&](int st, int buf) {
        const char* gsrc = mhat_g + (size_t)st * 32768;
        char* ldst = dyn + BUFA_OFF(buf);
#pragma unroll
        for (int i = 0; i < 4; ++i)
            gload16(gsrc + tid * 16 + i * 8192, ldst + tid * 16 + i * 8192);
    };
    auto stageB = [&](int st, int buf) {
        const char* gsrc = mblk_g + (size_t)st * 32768;
        char* ldst = dyn + BUFB_OFF(buf);
#pragma unroll
        for (int i = 0; i < 4; ++i)
            gload16(gsrc + tid * 16 + i * 8192, ldst + tid * 16 + i * 8192);
    };
    // phase-2 staging: mhat into the BUFB region (dead after phase 1)
    auto stageA2 = [&](int st, int buf) {
        const char* gsrc = mhat_g + (size_t)st * 32768;
        char* ldst = dyn + BUFB_OFF(buf);
#pragma unroll
        for (int i = 0; i < 4; ++i)
            gload16(gsrc + tid * 16 + i * 8192, ldst + tid * 16 + i * 8192);
    };

    stageA(0, 0); stageB(0, 0);

    // zero per-block wimg accumulator
#pragma unroll
    for (int i = 0; i < 4; ++i) wimg_l[i * 512 + tid] = 0.f;

    // ---- query norms ----
    {
        const int dp = tid >> 7, pp = tid & 127;
        const float* fp = fbase + (size_t)(dp * 64) * HW_PIX + p0 + pp;
        float ss = 0.f;
#pragma unroll 8
        for (int d = 0; d < 64; ++d) { const float v = fp[(size_t)d * HW_PIX]; ss += v * v; }
        sm_norm[dp * 128 + pp] = ss;
    }
    __syncthreads();
    if (tid < 128) {
        const float n2 = sm_norm[tid] + sm_norm[128 + tid] + sm_norm[256 + tid] + sm_norm[384 + tid];
        qs_lds[tid] = 1.0f / fmaxf(sqrtf(n2), 1e-12f);
    }
    __syncthreads();

    // ---- Q fragments (bf16 q-hat) ----
    short8 qfrag[2][8];
#pragma unroll
    for (int tq = 0; tq < 2; ++tq) {
        const int q = 32 * wq + 16 * tq + l15;
        const float qs = qs_lds[q];
        const float* fq = fbase + p0 + q;
#pragma unroll
        for (int kk = 0; kk < 8; ++kk) {
            union { short8 s; unsigned u[4]; } fr;
#pragma unroll
            for (int jp = 0; jp < 4; ++jp) {
                const int d = 32 * kk + 8 * g + 2 * jp;
                fr.u[jp] = pack2(fq[(size_t)d * HW_PIX] * qs, fq[(size_t)(d + 1) * HW_PIX] * qs);
            }
            qfrag[tq][kk] = fr.s;
        }
    }

    const int srow = 32 * ws + l15;

    // ================= PHASE 1: Z, U, O_unnorm =================
    float Zp[2] = {0.f, 0.f}, Up[2] = {0.f, 0.f};
    f32x4 acc_o[2][16] = {};
    __syncthreads();
    int cur = 0;
    for (int st = 0; st < 32; ++st) {
        if (st < 31) { stageA(st + 1, cur ^ 1); stageB(st + 1, cur ^ 1); }
        f32x4 acc[2][2] = {};
        qkt(dyn + BUFA_OFF(cur), qfrag, srow, g, l15, acc);
        float ev[2][2][4];
#pragma unroll
        for (int ts = 0; ts < 2; ++ts)
#pragma unroll
            for (int tq = 0; tq < 2; ++tq)
#pragma unroll
                for (int r = 0; r < 4; ++r) {
                    const float sim2 = acc[ts][tq][r];       // log2-domain
                    const float e = exp2f(sim2);
                    ev[ts][tq][r] = e;
                    Zp[tq] += e; Up[tq] += e * sim2;
                }
        // repack P -> A-fragments (bf16 raw e), in registers
        short8 pfrag[2];
#pragma unroll
        for (int tq = 0; tq < 2; ++tq) {
            const unsigned u00 = pack2(ev[0][tq][0], ev[0][tq][1]);
            const unsigned u01 = pack2(ev[0][tq][2], ev[0][tq][3]);
            const unsigned u10 = pack2(ev[1][tq][0], ev[1][tq][1]);
            const unsigned u11 = pack2(ev[1][tq][2], ev[1][tq][3]);
            const int sA = l15 + 32 * (g & 1);
            const int sB = sA + 16;
            const unsigned a00 = __shfl((int)u00, sA), a10 = __shfl((int)u10, sA);
            const unsigned a01 = __shfl((int)u01, sA), a11 = __shfl((int)u11, sA);
            const unsigned b00 = __shfl((int)u00, sB), b10 = __shfl((int)u10, sB);
            const unsigned b01 = __shfl((int)u01, sB), b11 = __shfl((int)u11, sB);
            const bool hi = (lane & 32) != 0;
            union { short8 s; unsigned u[4]; } fr;
            fr.u[0] = hi ? a10 : a00;
            fr.u[1] = hi ? a11 : a01;
            fr.u[2] = hi ? b10 : b00;
            fr.u[3] = hi ? b11 : b01;
            pfrag[tq] = fr.s;
        }
        const char* mb = dyn + BUFB_OFF(cur);
        const int cswz = (((4 * ws + g) ^ (l15 & 7)) << 4);
#pragma unroll
        for (int Dt = 0; Dt < 16; ++Dt) {
            const int d = 16 * Dt + l15;
            const short8 bf = *reinterpret_cast<const short8*>(mb + d * 128 + cswz);
            acc_o[0][Dt] = __builtin_amdgcn_mfma_f32_16x16x32_bf16(pfrag[0], bf, acc_o[0][Dt], 0, 0, 0);
            acc_o[1][Dt] = __builtin_amdgcn_mfma_f32_16x16x32_bf16(pfrag[1], bf, acc_o[1][Dt], 0, 0, 0);
        }
        __syncthreads();
        cur ^= 1;
    }

    // ---- Z/U reduction, rZ, entropy (H = lnZ - ln2*U2/Z) ----
#pragma unroll
    for (int tq = 0; tq < 2; ++tq) {
        Zp[tq] += __shfl_xor(Zp[tq], 16); Zp[tq] += __shfl_xor(Zp[tq], 32);
        Up[tq] += __shfl_xor(Up[tq], 16); Up[tq] += __shfl_xor(Up[tq], 32);
    }
    if (lane < 16) {
#pragma unroll
        for (int tq = 0; tq < 2; ++tq) {
            zb[ws][wq][tq][lane] = Zp[tq];
            ub[ws][wq][tq][lane] = Up[tq];
        }
    }
    __syncthreads();
    {
        float Zf[2], Uf[2], rZ[2];
#pragma unroll
        for (int tq = 0; tq < 2; ++tq) {
            Zf[tq] = Zp[tq] + zb[1 - ws][wq][tq][l15];
            Uf[tq] = Up[tq] + ub[1 - ws][wq][tq][l15];
            rZ[tq] = 1.0f / Zf[tq];
        }
        if (ws == 0 && lane < 16) {
            rZbuf[32 * wq + l15]      = rZ[0];
            rZbuf[32 * wq + 16 + l15] = rZ[1];
            float ent = 0.f;
#pragma unroll
            for (int tq = 0; tq < 2; ++tq) ent += __logf(Zf[tq]) - LN2F * Uf[tq] * rZ[tq];
            ent += __shfl_xor(ent, 1); ent += __shfl_xor(ent, 2);
            ent += __shfl_xor(ent, 4); ent += __shfl_xor(ent, 8);
            if (lane == 0) entb[wq] = ent;
        }
    }
    __syncthreads();
    if (tid == 0)
        atomicAdd(out + OUT_ENT_IDX, (entb[0] + entb[1] + entb[2] + entb[3]) * (1.0f / 32768.0f));

    // issue phase-2 tile 0 stage now: latency hides under the epilogue
    stageA2(0, 0);

    // ---- epilogue (frees acc_o before wimg phase); uses dyn[0..20K) only ----
    float rZq[2][4];
#pragma unroll
    for (int tq = 0; tq < 2; ++tq)
#pragma unroll
        for (int r = 0; r < 4; ++r)
            rZq[tq][r] = rZbuf[32 * wq + 16 * tq + 4 * g + r];

#pragma unroll
    for (int Dt = 0; Dt < 16; ++Dt) {
        if (ws == 1) {
#pragma unroll
            for (int tq = 0; tq < 2; ++tq)
                *reinterpret_cast<f32x4*>(dyn + ((wq * 2 + tq) * 64 + lane) * 16) = acc_o[tq][Dt];
        }
        __syncthreads();
        if (ws == 0) {
#pragma unroll
            for (int tq = 0; tq < 2; ++tq) {
                const f32x4 other = *reinterpret_cast<const f32x4*>(dyn + ((wq * 2 + tq) * 64 + lane) * 16);
#pragma unroll
                for (int r = 0; r < 4; ++r) {
                    const float o = (acc_o[tq][Dt][r] + other[r]) * rZq[tq][r];
                    const float a = fabsf(o);
                    const float lam = fminf(0.005f / (a + 1e-8f), 1.0f);
                    const float val = copysignf(a * (1.0f - lam), o);
                    const int q = 32 * wq + 16 * tq + 4 * g + r;
                    *reinterpret_cast<float*>(dyn + 8192 + q * 84 + l15 * 4) = val;
                }
            }
        }
        __syncthreads();
#pragma unroll
        for (int i = 0; i < 4; ++i) {
            const int flat = i * 512 + tid;
            const int dd = flat >> 7, q = flat & 127;
            const float val = *reinterpret_cast<const float*>(dyn + 8192 + q * 84 + dd * 4);
            out[((size_t)b * 256 + Dt * 16 + dd) * HW_PIX + p0 + q] = val;
        }
        __syncthreads();
    }

    // ============ PHASE 2: wimg (LDS-staged dbuf, swapped-operand QK^T) =====
    {
        float rzq[2][4];
#pragma unroll
        for (int tq = 0; tq < 2; ++tq)
#pragma unroll
            for (int r = 0; r < 4; ++r)
                rzq[tq][r] = rZbuf[32 * wq + 16 * tq + 4 * g + r] * (1.0f / 1024.0f);

        int cur2 = 0;
        for (int st = 0; st < 32; ++st) {
            if (st < 31) stageA2(st + 1, cur2 ^ 1);
            const char* mh = dyn + BUFB_OFF(cur2);
            f32x4 a2[2][2] = {};   // [sb][tq]; C rows = q, cols = s
#pragma unroll
            for (int kk = 0; kk < 8; ++kk) {
                const int c0 = ((4 * kk + g) ^ (l15 & 7)) << 4;
                const short8 m0 = *reinterpret_cast<const short8*>(mh + srow * 512 + c0);
                const short8 m1 = *reinterpret_cast<const short8*>(mh + (srow + 16) * 512 + c0);
                a2[0][0] = __builtin_amdgcn_mfma_f32_16x16x32_bf16(qfrag[0][kk], m0, a2[0][0], 0, 0, 0);
                a2[0][1] = __builtin_amdgcn_mfma_f32_16x16x32_bf16(qfrag[1][kk], m0, a2[0][1], 0, 0, 0);
                a2[1][0] = __builtin_amdgcn_mfma_f32_16x16x32_bf16(qfrag[0][kk], m1, a2[1][0], 0, 0, 0);
                a2[1][1] = __builtin_amdgcn_mfma_f32_16x16x32_bf16(qfrag[1][kk], m1, a2[1][1], 0, 0, 0);
            }
#pragma unroll
            for (int sb = 0; sb < 2; ++sb) {
                float v = 0.f;
#pragma unroll
                for (int tq = 0; tq < 2; ++tq)
#pragma unroll
                    for (int r = 0; r < 4; ++r)
                        v += exp2f(a2[sb][tq][r]) * rzq[tq][r];
                v += __shfl_xor(v, 16);
                v += __shfl_xor(v, 32);
                if (lane < 16)
                    atomicAdd(&wimg_l[st * 64 + 32 * ws + 16 * sb + l15], v);
            }
            __syncthreads();
            cur2 ^= 1;
        }
    }
    {
        float* wimg_gb = out + OUT_WIMG_IDX + (size_t)b * S_SLOTS;
#pragma unroll
        for (int i = 0; i < 4; ++i) {
            const int s = i * 512 + tid;
            atomicAdd(wimg_gb + s, wimg_l[s]);
        }
    }
}

extern "C" void kernel_launch(void* const* d_in, const int* in_sizes, int n_in,
                              void* d_out, int out_size, void* d_ws, size_t ws_size,
                              hipStream_t stream) {
    const float* feat = (const float*)d_in[0];   // (32,256,32,32) f32
    const float* mem  = (const float*)d_in[1];   // (2048,256) f32
    float* out = (float*)d_out;

    unsigned short* mhat_g = (unsigned short*)d_ws;                       // 1 MB
    unsigned short* mblk_g = (unsigned short*)((char*)d_ws + (1 << 20));  // 1 MB

    // zero entropy + weights_image (retrieved fully overwritten)
    hipMemsetAsync((char*)d_out + (size_t)OUT_ENT_IDX * 4, 0,
                   (size_t)(1 + 32 * S_SLOTS) * 4, stream);

    k_prep<<<256, 64, 0, stream>>>(mem, mhat_g, mblk_g);

    hipFuncSetAttribute((const void*)k_fused,
                        hipFuncAttributeMaxDynamicSharedMemorySize, FUSED_DYN);
    k_fused<<<256, 512, FUSED_DYN, stream>>>(feat, (const char*)mhat_g,
                                             (const char*)mblk_g, out);
}

// Round 10
// 220.881 us; speedup vs baseline: 1.2895x; 1.2412x over previous
//
#include <hip/hip_runtime.h>
#include <cstdint>
#include <cstddef>

// B=32, D=256, H=W=32 (HW=1024), S=2048, N=32768
#define D_DIM 256
#define S_SLOTS 2048
#define HW_PIX 1024
#define OUT_ENT_IDX 8388608
#define OUT_WIMG_IDX 8388609

// k_fused dynamic LDS
#define BUFA_OFF(b) ((b) * 32768)            // phase-1 mhat tiles: [0, 65536)
#define BUFB_OFF(b) (65536 + (b) * 32768)    // phase-1 mblk / fallback phase-2 mhat
#define WIMG_OFF    131072                   // f32[2048]
#define FUSED_DYN   139264

#define PST_BYTES   134217728ULL             // 256 blocks * 512 KB
#define WS_NEEDED   ((2ULL << 20) + PST_BYTES)

#define LOG2E_20 28.853900817779268f
#define LN2F     0.6931471805599453f

using short8 = __attribute__((ext_vector_type(8))) short;
using f32x4  = __attribute__((ext_vector_type(4))) float;

__device__ __forceinline__ unsigned short f2bf(float x) {
    union { float f; unsigned u; } v; v.f = x;
    unsigned r = v.u + 0x7FFF + ((v.u >> 16) & 1);   // RNE
    return (unsigned short)(r >> 16);
}
__device__ __forceinline__ float bf2f(unsigned short h) {
    union { unsigned u; float f; } v; v.u = ((unsigned)h) << 16; return v.f;
}
__device__ __forceinline__ unsigned pack2(float lo, float hi) {
    return (unsigned)f2bf(lo) | ((unsigned)f2bf(hi) << 16);
}
__device__ __forceinline__ void gload16(const void* g, void* l) {
    __builtin_amdgcn_global_load_lds(
        (const __attribute__((address_space(1))) unsigned int*)g,
        (__attribute__((address_space(3))) unsigned int*)l, 16, 0, 0);
}

// ---------------- prep: norms + two bf16 layouts into ws (coalesced) --------
// mhatg: [s][d] bf16, scaled by (20*log2e)/||m_s||, chunk swizzle ^(s&7) (1MB)
// mblkg: [tile][d 256][sloc 64] bf16 raw, chunk swizzle ^(d&7)           (1MB)
__global__ __launch_bounds__(64) void k_prep(const float* __restrict__ mem,
                                             unsigned short* __restrict__ mhatg,
                                             unsigned short* __restrict__ mblkg) {
    __shared__ float lm[8 * 257];
    __shared__ float scl[8];
    const int l = threadIdx.x, blk = blockIdx.x;
    const int tile = blk >> 3, oct = blk & 7;
    const int s0 = tile * 64 + oct * 8;
    const float* src = mem + (size_t)s0 * D_DIM;
#pragma unroll
    for (int i = 0; i < 8; ++i) {
        const int f4 = i * 64 + l;
        const int r = f4 >> 6, dq = (f4 & 63) * 4;
        const float4 v = reinterpret_cast<const float4*>(src)[f4];
        float* p = lm + r * 257 + dq;
        p[0] = v.x; p[1] = v.y; p[2] = v.z; p[3] = v.w;
    }
    __syncthreads();
    {
        const int r = l >> 3, pp = l & 7;
        float ss = 0.f;
#pragma unroll 8
        for (int d = 0; d < 32; ++d) { const float v = lm[r * 257 + pp * 32 + d]; ss += v * v; }
        ss += __shfl_xor(ss, 1); ss += __shfl_xor(ss, 2); ss += __shfl_xor(ss, 4);
        if (pp == 0) scl[r] = LOG2E_20 / fmaxf(sqrtf(ss), 1e-12f);
    }
    __syncthreads();
#pragma unroll
    for (int i = 0; i < 4; ++i) {
        const int c = i * 64 + l, r = c >> 5, k = c & 31;
        const int s_g = s0 + r;
        const float sc = scl[r];
        const float* p = lm + r * 257 + ((k ^ (s_g & 7)) * 8);
        union { short8 s; unsigned short h[8]; } o;
#pragma unroll
        for (int j = 0; j < 8; ++j) o.h[j] = f2bf(p[j] * sc);
        *reinterpret_cast<short8*>((char*)mhatg + (size_t)s_g * 512 + k * 16) = o.s;
    }
#pragma unroll
    for (int i = 0; i < 4; ++i) {
        const int d = i * 64 + l;
        const int k = oct ^ (d & 7);
        union { short8 s; unsigned short h[8]; } o;
#pragma unroll
        for (int j = 0; j < 8; ++j) o.h[j] = f2bf(lm[j * 257 + d]);
        *reinterpret_cast<short8*>((char*)mblkg + (size_t)tile * 32768 + d * 128 + k * 16) = o.s;
    }
}

// ---------------- k_fused ----------------------------------------------------
__device__ __forceinline__ void qkt(const char* mh, const short8 (&qfrag)[2][8],
                                    int srow, int g, int l15, f32x4 (&acc)[2][2]) {
#pragma unroll
    for (int kk = 0; kk < 8; ++kk) {
        const int c0 = ((4 * kk + g) ^ (l15 & 7)) << 4;
        const short8 a0 = *reinterpret_cast<const short8*>(mh + srow * 512 + c0);
        const short8 a1 = *reinterpret_cast<const short8*>(mh + (srow + 16) * 512 + c0);
        acc[0][0] = __builtin_amdgcn_mfma_f32_16x16x32_bf16(a0, qfrag[0][kk], acc[0][0], 0, 0, 0);
        acc[0][1] = __builtin_amdgcn_mfma_f32_16x16x32_bf16(a0, qfrag[1][kk], acc[0][1], 0, 0, 0);
        acc[1][0] = __builtin_amdgcn_mfma_f32_16x16x32_bf16(a1, qfrag[0][kk], acc[1][0], 0, 0, 0);
        acc[1][1] = __builtin_amdgcn_mfma_f32_16x16x32_bf16(a1, qfrag[1][kk], acc[1][1], 0, 0, 0);
    }
}

template <bool PST>
__global__ __launch_bounds__(512, 2) void k_fused(
    const float* __restrict__ feat, const char* __restrict__ mhat_g,
    const char* __restrict__ mblk_g, char* __restrict__ pst,
    float* __restrict__ out)
{
    extern __shared__ char dyn[];
    __shared__ float sm_norm[512];
    __shared__ float qs_lds[128];
    __shared__ float zb[2][4][2][16];
    __shared__ float ub[2][4][2][16];
    __shared__ float rZbuf[128];
    __shared__ float entb[4];

    const int tid  = threadIdx.x;
    const int lane = tid & 63;
    const int w    = tid >> 6;
    const int wq   = w & 3;
    const int ws   = w >> 2;
    const int l15  = lane & 15;
    const int g    = (lane >> 4) & 3;
    const int blk  = blockIdx.x;
    const int b    = blk >> 3;
    const int p0   = (blk & 7) * 128;
    const float* fbase = feat + (size_t)b * (D_DIM * HW_PIX);
    float* wimg_l = reinterpret_cast<float*>(dyn + WIMG_OFF);

    auto stageA = [&](int st, int buf) {
        const char* gsrc = mhat_g + (size_t)st * 32768;
        char* ldst = dyn + BUFA_OFF(buf);
#pragma unroll
        for (int i = 0; i < 4; ++i)
            gload16(gsrc + tid * 16 + i * 8192, ldst + tid * 16 + i * 8192);
    };
    auto stageB = [&](int st, int buf) {
        const char* gsrc = mblk_g + (size_t)st * 32768;
        char* ldst = dyn + BUFB_OFF(buf);
#pragma unroll
        for (int i = 0; i < 4; ++i)
            gload16(gsrc + tid * 16 + i * 8192, ldst + tid * 16 + i * 8192);
    };
    auto stageA2 = [&](int st, int buf) {     // fallback phase-2 staging
        const char* gsrc = mhat_g + (size_t)st * 32768;
        char* ldst = dyn + BUFB_OFF(buf);
#pragma unroll
        for (int i = 0; i < 4; ++i)
            gload16(gsrc + tid * 16 + i * 8192, ldst + tid * 16 + i * 8192);
    };

    stageA(0, 0); stageB(0, 0);

#pragma unroll
    for (int i = 0; i < 4; ++i) wimg_l[i * 512 + tid] = 0.f;

    // ---- query norms ----
    {
        const int dp = tid >> 7, pp = tid & 127;
        const float* fp = fbase + (size_t)(dp * 64) * HW_PIX + p0 + pp;
        float ss = 0.f;
#pragma unroll 8
        for (int d = 0; d < 64; ++d) { const float v = fp[(size_t)d * HW_PIX]; ss += v * v; }
        sm_norm[dp * 128 + pp] = ss;
    }
    __syncthreads();
    if (tid < 128) {
        const float n2 = sm_norm[tid] + sm_norm[128 + tid] + sm_norm[256 + tid] + sm_norm[384 + tid];
        qs_lds[tid] = 1.0f / fmaxf(sqrtf(n2), 1e-12f);
    }
    __syncthreads();

    // ---- Q fragments (bf16 q-hat) ----
    short8 qfrag[2][8];
#pragma unroll
    for (int tq = 0; tq < 2; ++tq) {
        const int q = 32 * wq + 16 * tq + l15;
        const float qs = qs_lds[q];
        const float* fq = fbase + p0 + q;
#pragma unroll
        for (int kk = 0; kk < 8; ++kk) {
            union { short8 s; unsigned u[4]; } fr;
#pragma unroll
            for (int jp = 0; jp < 4; ++jp) {
                const int d = 32 * kk + 8 * g + 2 * jp;
                fr.u[jp] = pack2(fq[(size_t)d * HW_PIX] * qs, fq[(size_t)(d + 1) * HW_PIX] * qs);
            }
            qfrag[tq][kk] = fr.s;
        }
    }

    const int srow = 32 * ws + l15;

    // ================= PHASE 1: Z, U, O_unnorm (+ P spill if PST) ===========
    float Zp[2] = {0.f, 0.f}, Up[2] = {0.f, 0.f};
    f32x4 acc_o[2][16] = {};
    __syncthreads();
    int cur = 0;
    for (int st = 0; st < 32; ++st) {
        if (st < 31) { stageA(st + 1, cur ^ 1); stageB(st + 1, cur ^ 1); }
        f32x4 acc[2][2] = {};
        qkt(dyn + BUFA_OFF(cur), qfrag, srow, g, l15, acc);
        float ev[2][2][4];
#pragma unroll
        for (int ts = 0; ts < 2; ++ts)
#pragma unroll
            for (int tq = 0; tq < 2; ++tq)
#pragma unroll
                for (int r = 0; r < 4; ++r) {
                    const float sim2 = acc[ts][tq][r];       // log2-domain
                    const float e = exp2f(sim2);
                    ev[ts][tq][r] = e;
                    Zp[tq] += e; Up[tq] += e * sim2;
                }
        // repack P -> A-fragments (bf16 raw e), in registers
        short8 pfrag[2];
#pragma unroll
        for (int tq = 0; tq < 2; ++tq) {
            const unsigned u00 = pack2(ev[0][tq][0], ev[0][tq][1]);
            const unsigned u01 = pack2(ev[0][tq][2], ev[0][tq][3]);
            const unsigned u10 = pack2(ev[1][tq][0], ev[1][tq][1]);
            const unsigned u11 = pack2(ev[1][tq][2], ev[1][tq][3]);
            const int sA = l15 + 32 * (g & 1);
            const int sB = sA + 16;
            const unsigned a00 = __shfl((int)u00, sA), a10 = __shfl((int)u10, sA);
            const unsigned a01 = __shfl((int)u01, sA), a11 = __shfl((int)u11, sA);
            const unsigned b00 = __shfl((int)u00, sB), b10 = __shfl((int)u10, sB);
            const unsigned b01 = __shfl((int)u01, sB), b11 = __shfl((int)u11, sB);
            const bool hi = (lane & 32) != 0;
            union { short8 s; unsigned u[4]; } fr;
            fr.u[0] = hi ? a10 : a00;
            fr.u[1] = hi ? a11 : a01;
            fr.u[2] = hi ? b10 : b00;
            fr.u[3] = hi ? b11 : b01;
            pfrag[tq] = fr.s;
        }
        if (PST) {   // spill e-fragments: 2 coalesced dwordx4 per thread
            char* pdst = pst + (size_t)blk * 524288 + (size_t)st * 16384
                         + w * 2048 + lane * 16;
            *reinterpret_cast<short8*>(pdst)        = pfrag[0];
            *reinterpret_cast<short8*>(pdst + 1024) = pfrag[1];
        }
        const char* mb = dyn + BUFB_OFF(cur);
        const int cswz = (((4 * ws + g) ^ (l15 & 7)) << 4);
#pragma unroll
        for (int Dt = 0; Dt < 16; ++Dt) {
            const int d = 16 * Dt + l15;
            const short8 bf = *reinterpret_cast<const short8*>(mb + d * 128 + cswz);
            acc_o[0][Dt] = __builtin_amdgcn_mfma_f32_16x16x32_bf16(pfrag[0], bf, acc_o[0][Dt], 0, 0, 0);
            acc_o[1][Dt] = __builtin_amdgcn_mfma_f32_16x16x32_bf16(pfrag[1], bf, acc_o[1][Dt], 0, 0, 0);
        }
        __syncthreads();
        cur ^= 1;
    }

    // ---- Z/U reduction, rZ, entropy (H = lnZ - ln2*U2/Z) ----
#pragma unroll
    for (int tq = 0; tq < 2; ++tq) {
        Zp[tq] += __shfl_xor(Zp[tq], 16); Zp[tq] += __shfl_xor(Zp[tq], 32);
        Up[tq] += __shfl_xor(Up[tq], 16); Up[tq] += __shfl_xor(Up[tq], 32);
    }
    if (lane < 16) {
#pragma unroll
        for (int tq = 0; tq < 2; ++tq) {
            zb[ws][wq][tq][lane] = Zp[tq];
            ub[ws][wq][tq][lane] = Up[tq];
        }
    }
    __syncthreads();
    {
        float Zf[2], Uf[2], rZ[2];
#pragma unroll
        for (int tq = 0; tq < 2; ++tq) {
            Zf[tq] = Zp[tq] + zb[1 - ws][wq][tq][l15];
            Uf[tq] = Up[tq] + ub[1 - ws][wq][tq][l15];
            rZ[tq] = 1.0f / Zf[tq];
        }
        if (ws == 0 && lane < 16) {
            rZbuf[32 * wq + l15]      = rZ[0];
            rZbuf[32 * wq + 16 + l15] = rZ[1];
            float ent = 0.f;
#pragma unroll
            for (int tq = 0; tq < 2; ++tq) ent += __logf(Zf[tq]) - LN2F * Uf[tq] * rZ[tq];
            ent += __shfl_xor(ent, 1); ent += __shfl_xor(ent, 2);
            ent += __shfl_xor(ent, 4); ent += __shfl_xor(ent, 8);
            if (lane == 0) entb[wq] = ent;
        }
    }
    __syncthreads();
    if (tid == 0)
        atomicAdd(out + OUT_ENT_IDX, (entb[0] + entb[1] + entb[2] + entb[3]) * (1.0f / 32768.0f));

    if (!PST) stageA2(0, 0);   // fallback: prefetch phase-2 tile 0 under epilogue

    // ---- epilogue (frees acc_o) ----
    float rZq[2][4];
#pragma unroll
    for (int tq = 0; tq < 2; ++tq)
#pragma unroll
        for (int r = 0; r < 4; ++r)
            rZq[tq][r] = rZbuf[32 * wq + 16 * tq + 4 * g + r];

#pragma unroll
    for (int Dt = 0; Dt < 16; ++Dt) {
        if (ws == 1) {
#pragma unroll
            for (int tq = 0; tq < 2; ++tq)
                *reinterpret_cast<f32x4*>(dyn + ((wq * 2 + tq) * 64 + lane) * 16) = acc_o[tq][Dt];
        }
        __syncthreads();
        if (ws == 0) {
#pragma unroll
            for (int tq = 0; tq < 2; ++tq) {
                const f32x4 other = *reinterpret_cast<const f32x4*>(dyn + ((wq * 2 + tq) * 64 + lane) * 16);
#pragma unroll
                for (int r = 0; r < 4; ++r) {
                    const float o = (acc_o[tq][Dt][r] + other[r]) * rZq[tq][r];
                    const float a = fabsf(o);
                    const float lam = fminf(0.005f / (a + 1e-8f), 1.0f);
                    const float val = copysignf(a * (1.0f - lam), o);
                    const int q = 32 * wq + 16 * tq + 4 * g + r;
                    *reinterpret_cast<float*>(dyn + 8192 + q * 84 + l15 * 4) = val;
                }
            }
        }
        __syncthreads();
#pragma unroll
        for (int i = 0; i < 4; ++i) {
            const int flat = i * 512 + tid;
            const int dd = flat >> 7, q = flat & 127;
            const float val = *reinterpret_cast<const float*>(dyn + 8192 + q * 84 + dd * 4);
            out[((size_t)b * 256 + Dt * 16 + dd) * HW_PIX + p0 + q] = val;
        }
        __syncthreads();
    }

    // ================= PHASE 2: wimg =================
    if (PST) {
        // stream spilled P back (own bytes only -> no fence), weight, reduce.
        float rz2[2];
        rz2[0] = rZbuf[32 * wq + l15]      * (1.0f / 1024.0f);
        rz2[1] = rZbuf[32 * wq + 16 + l15] * (1.0f / 1024.0f);
        const int grp = lane >> 4;
        const char* pbase = pst + (size_t)blk * 524288 + w * 2048 + lane * 16;
        for (int st = 0; st < 32; ++st) {
            const char* p = pbase + (size_t)st * 16384;
            union { short8 s; unsigned short h[8]; } e0, e1;
            e0.s = *reinterpret_cast<const short8*>(p);
            e1.s = *reinterpret_cast<const short8*>(p + 1024);
            float v[8];
#pragma unroll
            for (int j = 0; j < 8; ++j)
                v[j] = bf2f(e0.h[j]) * rz2[0] + bf2f(e1.h[j]) * rz2[1];
#pragma unroll
            for (int o = 1; o <= 8; o <<= 1)
#pragma unroll
                for (int j = 0; j < 8; ++j) v[j] += __shfl_xor(v[j], o);
            if (l15 == 0) {
#pragma unroll
                for (int j = 0; j < 8; ++j)
                    atomicAdd(&wimg_l[st * 64 + 32 * ws + 8 * grp + j], v[j]);
            }
        }
    } else {
        // fallback: LDS-staged swapped-operand QK^T recompute (r9 path)
        float rzq[2][4];
#pragma unroll
        for (int tq = 0; tq < 2; ++tq)
#pragma unroll
            for (int r = 0; r < 4; ++r)
                rzq[tq][r] = rZbuf[32 * wq + 16 * tq + 4 * g + r] * (1.0f / 1024.0f);

        int cur2 = 0;
        for (int st = 0; st < 32; ++st) {
            if (st < 31) stageA2(st + 1, cur2 ^ 1);
            const char* mh = dyn + BUFB_OFF(cur2);
            f32x4 a2[2][2] = {};
#pragma unroll
            for (int kk = 0; kk < 8; ++kk) {
                const int c0 = ((4 * kk + g) ^ (l15 & 7)) << 4;
                const short8 m0 = *reinterpret_cast<const short8*>(mh + srow * 512 + c0);
                const short8 m1 = *reinterpret_cast<const short8*>(mh + (srow + 16) * 512 + c0);
                a2[0][0] = __builtin_amdgcn_mfma_f32_16x16x32_bf16(qfrag[0][kk], m0, a2[0][0], 0, 0, 0);
                a2[0][1] = __builtin_amdgcn_mfma_f32_16x16x32_bf16(qfrag[1][kk], m0, a2[0][1], 0, 0, 0);
                a2[1][0] = __builtin_amdgcn_mfma_f32_16x16x32_bf16(qfrag[0][kk], m1, a2[1][0], 0, 0, 0);
                a2[1][1] = __builtin_amdgcn_mfma_f32_16x16x32_bf16(qfrag[1][kk], m1, a2[1][1], 0, 0, 0);
            }
#pragma unroll
            for (int sb = 0; sb < 2; ++sb) {
                float v = 0.f;
#pragma unroll
                for (int tq = 0; tq < 2; ++tq)
#pragma unroll
                    for (int r = 0; r < 4; ++r)
                        v += exp2f(a2[sb][tq][r]) * rzq[tq][r];
                v += __shfl_xor(v, 16);
                v += __shfl_xor(v, 32);
                if (lane < 16)
                    atomicAdd(&wimg_l[st * 64 + 32 * ws + 16 * sb + l15], v);
            }
            __syncthreads();
            cur2 ^= 1;
        }
    }

    __syncthreads();
    {
        float* wimg_gb = out + OUT_WIMG_IDX + (size_t)b * S_SLOTS;
#pragma unroll
        for (int i = 0; i < 4; ++i) {
            const int s = i * 512 + tid;
            atomicAdd(wimg_gb + s, wimg_l[s]);
        }
    }
}

extern "C" void kernel_launch(void* const* d_in, const int* in_sizes, int n_in,
                              void* d_out, int out_size, void* d_ws, size_t ws_size,
                              hipStream_t stream) {
    const float* feat = (const float*)d_in[0];   // (32,256,32,32) f32
    const float* mem  = (const float*)d_in[1];   // (2048,256) f32
    float* out = (float*)d_out;

    unsigned short* mhat_g = (unsigned short*)d_ws;                       // 1 MB
    unsigned short* mblk_g = (unsigned short*)((char*)d_ws + (1 << 20));  // 1 MB
    char*           pst    = (char*)d_ws + (2 << 20);                     // 128 MB

    hipMemsetAsync((char*)d_out + (size_t)OUT_ENT_IDX * 4, 0,
                   (size_t)(1 + 32 * S_SLOTS) * 4, stream);

    k_prep<<<256, 64, 0, stream>>>(mem, mhat_g, mblk_g);

    if (ws_size >= WS_NEEDED) {
        hipFuncSetAttribute((const void*)k_fused<true>,
                            hipFuncAttributeMaxDynamicSharedMemorySize, FUSED_DYN);
        k_fused<true><<<256, 512, FUSED_DYN, stream>>>(
            feat, (const char*)mhat_g, (const char*)mblk_g, pst, out);
    } else {
        hipFuncSetAttribute((const void*)k_fused<false>,
                            hipFuncAttributeMaxDynamicSharedMemorySize, FUSED_DYN);
        k_fused<false><<<256, 512, FUSED_DYN, stream>>>(
            feat, (const char*)mhat_g, (const char*)mblk_g, pst, out);
    }
}